// Round 4
// baseline (144.621 us; speedup 1.0000x reference)
//
#include <hip/hip_runtime.h>
#include <hip/hip_bf16.h>

// N=10000 nodes, F=256, H=256, E=320000 edges.
//
// W1 = [W1a | W1b]:  U = x @ W1a^T + b1 (bias folded), V = x @ W1b^T
// out[e] = sigmoid(b2 + sum_j relu(U'[row][j] + V[col][j]) * W2[j])
// uv layout: uv[node][0:256]=U', uv[node][256:512]=V, bf16 (1 KB/row).
//
// NOTE (R3 profile): harness re-poison of d_ws (268 MB fill, ~44 us) sits
// inside the timed window — top-5 dispatches were all fillBufferAligned.
// Controllable portion is edge (~35 us) + gemm + convert.

typedef __attribute__((ext_vector_type(8))) short bf16x8;
typedef __attribute__((ext_vector_type(4))) float f32x4;

__device__ __forceinline__ unsigned short f2bf(float f) {
    __hip_bfloat16 h = __float2bfloat16(f);
    return *reinterpret_cast<unsigned short*>(&h);
}

// ---------------------------------------------------------------------------
// Kernel 0: convert W1 (256x512 fp32) to bf16. Tiny.
// ---------------------------------------------------------------------------
__global__ __launch_bounds__(256) void convert_w(const float* __restrict__ w1,
                                                 unsigned short* __restrict__ wb,
                                                 int nw4) {
    int i = blockIdx.x * 256 + threadIdx.x;
    if (i < nw4) {
        float4 v = ((const float4*)w1)[i];
        ushort4 o = {f2bf(v.x), f2bf(v.y), f2bf(v.z), f2bf(v.w)};
        ((ushort4*)wb)[i] = o;
    }
}

// ---------------------------------------------------------------------------
// Kernel 1: wave -> 16 rows x 256 cols (4 n-tiles of 64), grid (157, 2).
// y=0: U half (koff=0, fold b1). y=1: V half (koff=256).
// A frag converted fp32->bf16 once per ktile, amortized over 16 MFMAs
// (R3 amortized over only 4 and re-read x 8x -> 80 MB; now 20 MB).
// C/D: col=lane&15, row=(lane>>4)*4+reg.
// ---------------------------------------------------------------------------
__global__ __launch_bounds__(256) void gemm_mfma(const float* __restrict__ x,
                                                 const unsigned short* __restrict__ wb,
                                                 const float* __restrict__ b1,
                                                 unsigned short* __restrict__ uv,
                                                 int M) {
    const int wave = threadIdx.x >> 6;
    const int lane = threadIdx.x & 63;
    const int m0 = (blockIdx.x * 4 + wave) * 16;
    if (m0 >= M) return;
    const int half = blockIdx.y;               // 0: U, 1: V
    const int koff = half * 256;

    const int lm = lane & 15;
    const int lk = (lane >> 4) * 8;

    const int arow = m0 + lm;
    const float* aptr = x + (size_t)(arow < M ? arow : 0) * 256 + lk;
    // B frag t of n-tile nt: W1 row (nt*64 + t*16 + lm), k = koff + kt + lk
    const unsigned short* bptr = wb + (size_t)lm * 512 + koff + lk;

    f32x4 acc[4][4];
#pragma unroll
    for (int nt = 0; nt < 4; ++nt)
#pragma unroll
        for (int t = 0; t < 4; ++t) acc[nt][t] = f32x4{0.f, 0.f, 0.f, 0.f};

#pragma unroll 2
    for (int kt = 0; kt < 256; kt += 32) {
        float4 alo = *(const float4*)(aptr + kt);
        float4 ahi = *(const float4*)(aptr + kt + 4);
        bf16x8 a;
        a[0] = (short)f2bf(alo.x); a[1] = (short)f2bf(alo.y);
        a[2] = (short)f2bf(alo.z); a[3] = (short)f2bf(alo.w);
        a[4] = (short)f2bf(ahi.x); a[5] = (short)f2bf(ahi.y);
        a[6] = (short)f2bf(ahi.z); a[7] = (short)f2bf(ahi.w);
#pragma unroll
        for (int nt = 0; nt < 4; ++nt) {
            const unsigned short* bp = bptr + (size_t)nt * 64 * 512 + kt;
            bf16x8 b0 = *(const bf16x8*)(bp);
            bf16x8 b1f = *(const bf16x8*)(bp + 16 * 512);
            bf16x8 b2f = *(const bf16x8*)(bp + 32 * 512);
            bf16x8 b3f = *(const bf16x8*)(bp + 48 * 512);
            acc[nt][0] = __builtin_amdgcn_mfma_f32_16x16x32_bf16(a, b0,  acc[nt][0], 0, 0, 0);
            acc[nt][1] = __builtin_amdgcn_mfma_f32_16x16x32_bf16(a, b1f, acc[nt][1], 0, 0, 0);
            acc[nt][2] = __builtin_amdgcn_mfma_f32_16x16x32_bf16(a, b2f, acc[nt][2], 0, 0, 0);
            acc[nt][3] = __builtin_amdgcn_mfma_f32_16x16x32_bf16(a, b3f, acc[nt][3], 0, 0, 0);
        }
    }

    const int row0 = m0 + (lane >> 4) * 4;
#pragma unroll
    for (int nt = 0; nt < 4; ++nt) {
#pragma unroll
        for (int t = 0; t < 4; ++t) {
            const int ncol = nt * 64 + t * 16 + lm;          // 0..255 within half
            const float badd = half ? 0.f : b1[ncol];        // fold b1 into U
#pragma unroll
            for (int r = 0; r < 4; ++r) {
                if (row0 + r < M)
                    uv[(size_t)(row0 + r) * 512 + half * 256 + ncol] =
                        f2bf(acc[nt][t][r] + badd);
            }
        }
    }
}

// ---------------------------------------------------------------------------
// Kernel 2: 4 edges per wave (g = lane>>4 edge slot, c = lane&15 col chunk).
// Per lane: 32B of U' + 32B of V (uint4 x2 each), bf16 lo/hi extraction,
// float2 math (invites v_pk_add_f32 / v_pk_fma_f32), 4-step butterfly.
// b1 already folded into U' by the GEMM epilogue.
// ---------------------------------------------------------------------------
__global__ __launch_bounds__(256) void edge_kernel(const unsigned short* __restrict__ uv,
                                                   const int* __restrict__ ei,
                                                   const float* __restrict__ w2,
                                                   const float* __restrict__ b2p,
                                                   float* __restrict__ out, int E) {
    const int lane = threadIdx.x & 63;
    const int g = lane >> 4;
    const int c = lane & 15;
    const int wid = (blockIdx.x * blockDim.x + threadIdx.x) >> 6;
    const int nwav = (gridDim.x * blockDim.x) >> 6;
    const int nb = E >> 2;   // batches of 4 edges

    float w2r[16];
#pragma unroll
    for (int i = 0; i < 4; ++i)
        *(float4*)&w2r[i * 4] = *(const float4*)(w2 + c * 16 + i * 4);
    const float b2 = b2p[0];

    for (int b = wid; b < nb; b += nwav) {
        const int e = b * 4 + g;
        const int row = ei[e];
        const int col = ei[E + e];
        const unsigned int* up = (const unsigned int*)(uv + (size_t)row * 512 + c * 16);
        const unsigned int* vp = (const unsigned int*)(uv + (size_t)col * 512 + 256 + c * 16);

        unsigned int uw[8], vw[8];
        *(uint4*)&uw[0] = *(const uint4*)up;
        *(uint4*)&uw[4] = *(const uint4*)(up + 4);
        *(uint4*)&vw[0] = *(const uint4*)vp;
        *(uint4*)&vw[4] = *(const uint4*)(vp + 4);

        float2 p2 = {0.f, 0.f};
#pragma unroll
        for (int i = 0; i < 8; ++i) {
            float2 u2 = {__uint_as_float(uw[i] << 16),
                         __uint_as_float(uw[i] & 0xffff0000u)};
            float2 v2 = {__uint_as_float(vw[i] << 16),
                         __uint_as_float(vw[i] & 0xffff0000u)};
            float2 s2 = {u2.x + v2.x, u2.y + v2.y};
            s2.x = fmaxf(s2.x, 0.f);
            s2.y = fmaxf(s2.y, 0.f);
            p2.x = fmaf(s2.x, w2r[2 * i], p2.x);
            p2.y = fmaf(s2.y, w2r[2 * i + 1], p2.y);
        }
        float p = p2.x + p2.y;

#pragma unroll
        for (int off = 1; off < 16; off <<= 1)
            p += __shfl_xor(p, off, 64);

        if (c == 0) {
            out[e] = 1.f / (1.f + __expf(-(p + b2)));
        }
    }
}

extern "C" void kernel_launch(void* const* d_in, const int* in_sizes, int n_in,
                              void* d_out, int out_size, void* d_ws, size_t ws_size,
                              hipStream_t stream) {
    const float* x  = (const float*)d_in[0];
    const int*   ei = (const int*)d_in[1];
    const float* W1 = (const float*)d_in[2];
    const float* b1 = (const float*)d_in[3];
    const float* W2 = (const float*)d_in[4];
    const float* b2 = (const float*)d_in[5];
    float* out = (float*)d_out;

    const int N = in_sizes[0] / 256;   // 10000
    const int E = in_sizes[1] / 2;     // 320000

    unsigned short* uv = (unsigned short*)d_ws;        // N*512 bf16 (10.24 MB)
    unsigned short* wb = uv + (size_t)N * 512;         // 256*512 bf16 (256 KB)

    const int nw4 = (256 * 512) / 4;
    convert_w<<<(nw4 + 255) / 256, 256, 0, stream>>>(W1, wb, nw4);

    dim3 g((N / 16 + 3) / 4, 2);                       // (157, 2)
    gemm_mfma<<<g, 256, 0, stream>>>(x, wb, b1, uv, N);

    edge_kernel<<<2048, 256, 0, stream>>>(uv, ei, W2, b2, out, E);
}

// Round 5
// 131.033 us; speedup vs baseline: 1.1037x; 1.1037x over previous
//
#include <hip/hip_runtime.h>
#include <hip/hip_bf16.h>

// N=10000 nodes, F=256, H=256, E=320000 edges.
//
// W1 = [W1a | W1b]:  U' = x @ W1a^T + b1 (bias folded), V = x @ W1b^T
// out[e] = sigmoid(b2 + sum_j relu(U'[row][j] + V[col][j]) * W2[j])
// uv layout: uv[node][0:256]=U', uv[node][256:512]=V, bf16 (1 KB/row).
//
// R4 lesson: (157,2) grid = 314 blocks -> ~1 wave/SIMD -> gemm latency-bound
// at 46us (MfmaUtil 2%). R5: 625 blocks, A staged once per block in LDS
// (U and V share the same A = x[:,0:256]), B streamed from L2.
// Harness tax: 268MB ws re-poison fill (~45us) sits in every timed window.

typedef __attribute__((ext_vector_type(8))) short bf16x8;
typedef __attribute__((ext_vector_type(4))) float f32x4;

__device__ __forceinline__ unsigned short f2bf(float f) {
    __hip_bfloat16 h = __float2bfloat16(f);
    return *reinterpret_cast<unsigned short*>(&h);
}

// ---------------------------------------------------------------------------
// Kernel 0: convert W1 (256x512 fp32) to bf16. Tiny (~2us).
// ---------------------------------------------------------------------------
__global__ __launch_bounds__(256) void convert_w(const float* __restrict__ w1,
                                                 unsigned short* __restrict__ wb,
                                                 int nw4) {
    int i = blockIdx.x * 256 + threadIdx.x;
    if (i < nw4) {
        float4 v = ((const float4*)w1)[i];
        ushort4 o = {f2bf(v.x), f2bf(v.y), f2bf(v.z), f2bf(v.w)};
        ((ushort4*)wb)[i] = o;
    }
}

// ---------------------------------------------------------------------------
// Kernel 1: block = 16 rows x 512 cols. Wave w owns cols w*128..+127
// (8 n-tiles of 16 -> 8 f32x4 accs). Per ktile (K=32):
//   - 256 threads stage A (16x32 fp32 -> bf16) into LDS (double-buffered,
//     row stride 40 shorts: 20-bank skew -> only 2-way aliasing, free).
//   - each lane: 1x ds_read_b128 A-frag + 8x 16B B-frag loads (L2-resident
//     wb) + 8 MFMA 16x16x32.
// Cols <256 use W1[:, 0:256] (U half), cols >=256 use W1[:, 256:512] (V).
// C/D: col=lane&15, row=(lane>>4)*4+reg.
// ---------------------------------------------------------------------------
__global__ __launch_bounds__(256) void gemm_mfma(const float* __restrict__ x,
                                                 const unsigned short* __restrict__ wb,
                                                 const float* __restrict__ b1,
                                                 unsigned short* __restrict__ uv,
                                                 int M) {
    __shared__ unsigned short As[2][16][40];   // 5.1 KB, padded stride

    const int t    = threadIdx.x;
    const int wave = t >> 6;
    const int lane = t & 63;
    const int lm   = lane & 15;
    const int lq   = lane >> 4;
    const int lk   = lq * 8;
    const int m0   = blockIdx.x * 16;

    // staging mapping: thread t loads x[m0 + (t>>4)][kt + 2*(t&15) .. +1]
    const int srow = t >> 4;
    const int sk   = (t & 15) * 2;
    const int grow = m0 + srow;
    const float* sptr = x + (size_t)(grow < M ? grow : (M - 1)) * 256 + sk;

    // B: wave w -> global cols w*128+...; half = w>>1 selects W1 k-half.
    const int half    = wave >> 1;
    const int colbase = wave * 128;
    const int rowbase = (wave & 1) * 128;                 // W1 row base
    const unsigned short* bpre =
        wb + (size_t)(rowbase + lm) * 512 + half * 256 + lk;

    f32x4 acc[8];
#pragma unroll
    for (int j = 0; j < 8; ++j) acc[j] = f32x4{0.f, 0.f, 0.f, 0.f};

    float2 apref = *(const float2*)(sptr);                // ktile 0

#pragma unroll
    for (int it = 0; it < 8; ++it) {
        const int kt  = it * 32;
        const int cur = it & 1;

        // pack 2 bf16 and store to LDS (4B aligned)
        unsigned int lo = ((unsigned int)f2bf(apref.x));
        unsigned int hi = ((unsigned int)f2bf(apref.y)) << 16;
        *(unsigned int*)&As[cur][srow][sk] = lo | hi;

        if (it < 7) apref = *(const float2*)(sptr + kt + 32);   // prefetch

        __syncthreads();

        bf16x8 a = *(const bf16x8*)&As[cur][lm][lk];

#pragma unroll
        for (int j = 0; j < 8; ++j) {
            bf16x8 b = *(const bf16x8*)(bpre + (size_t)j * 16 * 512 + kt);
            acc[j] = __builtin_amdgcn_mfma_f32_16x16x32_bf16(a, b, acc[j], 0, 0, 0);
        }
    }

    const int row0 = m0 + lq * 4;
#pragma unroll
    for (int j = 0; j < 8; ++j) {
        const int col  = colbase + j * 16 + lm;           // 0..511
        const float badd = half ? 0.f : b1[col];          // fold b1 into U
#pragma unroll
        for (int r = 0; r < 4; ++r) {
            if (row0 + r < M)
                uv[(size_t)(row0 + r) * 512 + col] = f2bf(acc[j][r] + badd);
        }
    }
}

// ---------------------------------------------------------------------------
// Kernel 2: 4 edges per wave (g = lane>>4 edge slot, c = lane&15 col chunk).
// Per lane: 32B of U' + 32B of V (uint4 x2 each), bf16 lo/hi extraction,
// float2 math, 4-step butterfly over 16 lanes. b1 pre-folded into U'.
// ---------------------------------------------------------------------------
__global__ __launch_bounds__(256) void edge_kernel(const unsigned short* __restrict__ uv,
                                                   const int* __restrict__ ei,
                                                   const float* __restrict__ w2,
                                                   const float* __restrict__ b2p,
                                                   float* __restrict__ out, int E) {
    const int lane = threadIdx.x & 63;
    const int g = lane >> 4;
    const int c = lane & 15;
    const int wid = (blockIdx.x * blockDim.x + threadIdx.x) >> 6;
    const int nwav = (gridDim.x * blockDim.x) >> 6;
    const int nb = E >> 2;

    float w2r[16];
#pragma unroll
    for (int i = 0; i < 4; ++i)
        *(float4*)&w2r[i * 4] = *(const float4*)(w2 + c * 16 + i * 4);
    const float b2 = b2p[0];

    for (int b = wid; b < nb; b += nwav) {
        const int e = b * 4 + g;
        const int row = ei[e];
        const int col = ei[E + e];
        const unsigned int* up = (const unsigned int*)(uv + (size_t)row * 512 + c * 16);
        const unsigned int* vp = (const unsigned int*)(uv + (size_t)col * 512 + 256 + c * 16);

        unsigned int uw[8], vw[8];
        *(uint4*)&uw[0] = *(const uint4*)up;
        *(uint4*)&uw[4] = *(const uint4*)(up + 4);
        *(uint4*)&vw[0] = *(const uint4*)vp;
        *(uint4*)&vw[4] = *(const uint4*)(vp + 4);

        float2 p2 = {0.f, 0.f};
#pragma unroll
        for (int i = 0; i < 8; ++i) {
            float2 u2 = {__uint_as_float(uw[i] << 16),
                         __uint_as_float(uw[i] & 0xffff0000u)};
            float2 v2 = {__uint_as_float(vw[i] << 16),
                         __uint_as_float(vw[i] & 0xffff0000u)};
            float2 s2 = {u2.x + v2.x, u2.y + v2.y};
            s2.x = fmaxf(s2.x, 0.f);
            s2.y = fmaxf(s2.y, 0.f);
            p2.x = fmaf(s2.x, w2r[2 * i], p2.x);
            p2.y = fmaf(s2.y, w2r[2 * i + 1], p2.y);
        }
        float p = p2.x + p2.y;

#pragma unroll
        for (int off = 1; off < 16; off <<= 1)
            p += __shfl_xor(p, off, 64);

        if (c == 0) {
            out[e] = 1.f / (1.f + __expf(-(p + b2)));
        }
    }
}

extern "C" void kernel_launch(void* const* d_in, const int* in_sizes, int n_in,
                              void* d_out, int out_size, void* d_ws, size_t ws_size,
                              hipStream_t stream) {
    const float* x  = (const float*)d_in[0];
    const int*   ei = (const int*)d_in[1];
    const float* W1 = (const float*)d_in[2];
    const float* b1 = (const float*)d_in[3];
    const float* W2 = (const float*)d_in[4];
    const float* b2 = (const float*)d_in[5];
    float* out = (float*)d_out;

    const int N = in_sizes[0] / 256;   // 10000
    const int E = in_sizes[1] / 2;     // 320000

    unsigned short* uv = (unsigned short*)d_ws;        // N*512 bf16 (10.24 MB)
    unsigned short* wb = uv + (size_t)N * 512;         // 256*512 bf16 (256 KB)

    const int nw4 = (256 * 512) / 4;
    convert_w<<<(nw4 + 255) / 256, 256, 0, stream>>>(W1, wb, nw4);

    gemm_mfma<<<(N + 15) / 16, 256, 0, stream>>>(x, wb, b1, uv, N);

    edge_kernel<<<2048, 256, 0, stream>>>(uv, ei, W2, b2, out, E);
}